// Round 11
// baseline (214.574 us; speedup 1.0000x reference)
//
#include <hip/hip_runtime.h>
#include <hip/hip_bf16.h>

// Problem constants (B=4, C=256, H=W=64, groups=8, heads=4)
#define BB   4
#define CC   256
#define NN   4096      // H*W
#define NH   4
#define HD   64
#define NG   8
#define GSZ  32        // channels per group
#define EPSV 1e-5f
#define SCALE_L2E 0.18033688f   // 64^-0.5 * log2(e), folded into q so softmax uses raw exp2

typedef __bf16 bf16x8 __attribute__((ext_vector_type(8)));
typedef float  f32x4  __attribute__((ext_vector_type(4)));
typedef short  short4v __attribute__((ext_vector_type(4)));

#define MFMA16(a, b, c)  __builtin_amdgcn_mfma_f32_16x16x32_bf16((a), (b), (c), 0, 0, 0)
#define MFMAPV(a, b, c)  __builtin_amdgcn_mfma_f32_16x16x16bf16_1k((a), (b), (c), 0, 0, 0)

#if __has_builtin(__builtin_amdgcn_exp2f)
#define EXP2F __builtin_amdgcn_exp2f
#else
#define EXP2F exp2f
#endif

__device__ inline unsigned short f2bf(float f) {
    unsigned int u = __float_as_uint(f);
    u += 0x7fffu + ((u >> 16) & 1u);   // RNE
    return (unsigned short)(u >> 16);
}

// pack 4 fp32 -> 4 bf16 (truncate: uniform relative bias cancels in O/li) for PV A-operand
__device__ __forceinline__ short4v pk4(const f32x4& p) {
    alignas(8) unsigned int u[2];
    u[0] = __builtin_amdgcn_perm(__float_as_uint(p[1]), __float_as_uint(p[0]), 0x07060302u);
    u[1] = __builtin_amdgcn_perm(__float_as_uint(p[3]), __float_as_uint(p[2]), 0x07060302u);
    return *reinterpret_cast<short4v*>(u);
}

// async global->LDS, 16B per lane; LDS dest is wave-uniform base + lane*16
__device__ __forceinline__ void async_ld16(void* lds, const void* g) {
    __builtin_amdgcn_global_load_lds(
        (const __attribute__((address_space(1))) unsigned int*)g,
        (__attribute__((address_space(3))) unsigned int*)lds, 16, 0, 0);
}

// ---------------- kernel 1: gn stats (blocks 0..255) + weight cvt (blocks 256..1023) ----------------
__global__ void k_prep(const float* __restrict__ x, float* __restrict__ stats,
                       const float* __restrict__ wq, const float* __restrict__ wp,
                       unsigned short* __restrict__ oq, unsigned short* __restrict__ op) {
    int blk = blockIdx.x;
    int t = threadIdx.x;
    if (blk >= 256) {   // weight conversion
        int i = (blk - 256) * 256 + t;
        if (i < 3 * CC * CC) oq[i] = f2bf(wq[i]);
        if (i < CC * CC)     op[i] = f2bf(wp[i]);
        return;
    }
    int b = blk >> 6, g = (blk >> 3) & 7, s = blk & 7;
    const float* p = x + ((size_t)(b * CC + g * GSZ)) * NN + s * 16384;
    float s0 = 0.f, s1 = 0.f;
    #pragma unroll
    for (int i = 0; i < 64; ++i) { float v = p[i * 256 + t]; s0 += v; s1 += v * v; }
    #pragma unroll
    for (int m = 1; m <= 32; m <<= 1) { s0 += __shfl_xor(s0, m); s1 += __shfl_xor(s1, m); }
    __shared__ float ls[8];
    int w = t >> 6;
    if ((t & 63) == 0) { ls[w * 2] = s0; ls[w * 2 + 1] = s1; }
    __syncthreads();
    if (t == 0) {
        float a0 = ls[0] + ls[2] + ls[4] + ls[6];
        float a1 = ls[1] + ls[3] + ls[5] + ls[7];
        atomicAdd(&stats[(b * NG + g) * 2 + 0], a0);
        atomicAdd(&stats[(b * NG + g) * 2 + 1], a1);
    }
}

// ------- kernel 2: groupnorm apply + transpose -> ht[b][n][c] (bf16) -------
__global__ void k_gnapply(const float* __restrict__ x, const float* __restrict__ gw,
                          const float* __restrict__ gb, const float* __restrict__ stats,
                          unsigned short* __restrict__ ht) {
    int b = blockIdx.z, ct = blockIdx.y, nt = blockIdx.x;
    int c0 = ct * 32, n0 = nt * 64;
    int t = threadIdx.x;
    __shared__ float tile[32][65];
    const float* xp = x + ((size_t)(b * CC + c0)) * NN + n0;
    int cl = t >> 6, nl = t & 63;
    #pragma unroll
    for (int p = 0; p < 8; ++p)
        tile[p * 4 + cl][nl] = xp[(size_t)(p * 4 + cl) * NN + nl];
    float sum = stats[(b * NG + ct) * 2 + 0];
    float ssq = stats[(b * NG + ct) * 2 + 1];
    float mean = sum * (1.0f / 131072.0f);
    float var  = ssq * (1.0f / 131072.0f) - mean * mean;
    float inv  = rsqrtf(var + EPSV);
    __syncthreads();
    int nw = t >> 2, ci = (t & 3) * 8;
    alignas(16) unsigned short o8[8];
    #pragma unroll
    for (int j = 0; j < 8; ++j) {
        int c = c0 + ci + j;
        float v = (tile[ci + j][nw] - mean) * inv * gw[c] + gb[c];
        o8[j] = f2bf(v);
    }
    *reinterpret_cast<uint4*>(ht + ((size_t)(b * NN + n0 + nw)) * CC + c0 + ci) =
        *reinterpret_cast<const uint4*>(o8);
}

// ---------------- kernel 3: QKV GEMM, 128x128 tile, double-buffered LDS ----------------
__global__ void __launch_bounds__(256)
k_qkv(const unsigned short* __restrict__ ht, const unsigned short* __restrict__ wq,
      const float* __restrict__ qb,
      unsigned short* __restrict__ qt, unsigned short* __restrict__ kt,
      unsigned short* __restrict__ vt) {
    int bx = blockIdx.x, by = blockIdx.y;
    int t = threadIdx.x, wave = t >> 6, lane = t & 63;
    int l15 = lane & 15, quad = lane >> 4;
    int wm = wave >> 1, wn = wave & 1;

    __shared__ alignas(16) unsigned char At[2][8192];   // [128 rows][32 c] bf16, 64B rows
    __shared__ alignas(16) unsigned char Bt[2][8192];

    const char* Ag = (const char*)wq + (size_t)by * 65536;
    const char* Bg = (const char*)ht + (size_t)bx * 65536;
    int row0 = t >> 2, slot = t & 3;                    // chunk t
    size_t a0 = (size_t)row0 * 512 + slot * 16;
    size_t a1 = a0 + 64 * 512;                          // chunk t+256
    unsigned int dst0 = wave * 1024;                    // lane*16 added by HW

    auto stage = [&](int buf, int kk) {
        size_t ko = (size_t)kk * 64;
        async_ld16(At[buf] + dst0,        Ag + a0 + ko);
        async_ld16(At[buf] + 4096 + dst0, Ag + a1 + ko);
        async_ld16(Bt[buf] + dst0,        Bg + a0 + ko);
        async_ld16(Bt[buf] + 4096 + dst0, Bg + a1 + ko);
    };

    f32x4 acc[4][4];
    #pragma unroll
    for (int i = 0; i < 4; ++i)
        #pragma unroll
        for (int j = 0; j < 4; ++j) acc[i][j] = (f32x4){0.f, 0.f, 0.f, 0.f};

    stage(0, 0);
    __syncthreads();

    for (int kk = 0; kk < 8; ++kk) {
        int cur = kk & 1;
        if (kk < 7) stage(cur ^ 1, kk + 1);
        bf16x8 af[4], bf[4];
        #pragma unroll
        for (int f = 0; f < 4; ++f) {
            af[f] = *reinterpret_cast<const bf16x8*>(At[cur] + (wm * 64 + f * 16 + l15) * 64 + quad * 16);
            bf[f] = *reinterpret_cast<const bf16x8*>(Bt[cur] + (wn * 64 + f * 16 + l15) * 64 + quad * 16);
        }
        #pragma unroll
        for (int fm = 0; fm < 4; ++fm)
            #pragma unroll
            for (int fn = 0; fn < 4; ++fn)
                acc[fm][fn] = MFMA16(af[fm], bf[fn], acc[fm][fn]);
        __syncthreads();
    }

    int s = by >> 1;
    int nn0 = bx * 128;
    int b = nn0 >> 12, nbase = nn0 & 4095;
    #pragma unroll
    for (int fm = 0; fm < 4; ++fm) {
        int o = by * 128 + wm * 64 + fm * 16 + quad * 4;
        int h = (o >> 6) & 3, d0 = o & 63;
        float bias[4];
        #pragma unroll
        for (int r = 0; r < 4; ++r) bias[r] = qb[o + r];
        #pragma unroll
        for (int fn = 0; fn < 4; ++fn) {
            int n = nbase + wn * 64 + fn * 16 + l15;
            if (s == 0) {
                alignas(8) unsigned short o4[4];
                #pragma unroll
                for (int r = 0; r < 4; ++r) o4[r] = f2bf((acc[fm][fn][r] + bias[r]) * SCALE_L2E);
                *reinterpret_cast<uint2*>(qt + (((size_t)(b * NH + h) * NN) + n) * HD + d0) =
                    *reinterpret_cast<const uint2*>(o4);
            } else if (s == 1) {
                alignas(8) unsigned short o4[4];
                #pragma unroll
                for (int r = 0; r < 4; ++r) o4[r] = f2bf(acc[fm][fn][r] + bias[r]);
                *reinterpret_cast<uint2*>(kt + (((size_t)(b * NH + h) * NN) + n) * HD + d0) =
                    *reinterpret_cast<const uint2*>(o4);
            } else {
                #pragma unroll
                for (int r = 0; r < 4; ++r)
                    vt[((size_t)(b * NH + h) * HD + d0 + r) * NN + n] = f2bf(acc[fm][fn][r] + bias[r]);
            }
        }
    }
}

// ---------------- kernel 4: flash attention, k-split 2, no VGPR cap ----------------
// grid (32 q-tiles of 128, B*NH, 2 key-splits); block 256 = 4 waves; wave owns 32 queries.
// __launch_bounds__(256) only: LDS (32 KB dbuf) caps at 4 blocks/CU = 4 waves/SIMD, so
// let the allocator use up to 128 VGPRs instead of squeezing to 64 with rematerialization.
__global__ void __launch_bounds__(256)
k_attn(const unsigned short* __restrict__ qt, const unsigned short* __restrict__ kt,
       const unsigned short* __restrict__ vt,
       unsigned short* __restrict__ op0, unsigned short* __restrict__ op1,
       float* __restrict__ lip) {
    int bh = blockIdx.y;
    int split = blockIdx.z;
    int t = threadIdx.x, wave = t >> 6, lane = t & 63;
    int l15 = lane & 15, quad = lane >> 4;
    int qbase = blockIdx.x * 128 + wave * 32;
    int kbase = split * 2048;
    const unsigned short* qp = qt + (size_t)bh * NN * HD;
    const unsigned short* kp = kt + (size_t)bh * NN * HD;
    const unsigned short* vp = vt + (size_t)bh * HD * NN;

    __shared__ alignas(16) unsigned char kbuf[2][8192];   // [64 keys][128 B]
    __shared__ alignas(16) unsigned char vbuf[2][8192];   // [64 d][128 B]

    int lr8 = lane >> 3, lc8 = lane & 7;
    int swz = lc8 ^ lr8;
    const char* ksrc = (const char*)kp + (size_t)(kbase + wave * 16 + lr8) * 128 + swz * 16;
    const char* vsrc = (const char*)vp + (size_t)(wave * 16 + lr8) * 8192 + (size_t)kbase * 2 + swz * 16;
    unsigned int dstw = wave * 2048;                // + lane*16 by HW

    auto stage = [&](int buf) {                     // stages next 64-key tile, advances
        async_ld16(kbuf[buf] + dstw,        ksrc);
        async_ld16(kbuf[buf] + dstw + 1024, ksrc + 1024);       // K rows +8
        ksrc += 8192;
        async_ld16(vbuf[buf] + dstw,        vsrc);
        async_ld16(vbuf[buf] + dstw + 1024, vsrc + 8 * 8192);   // d-rows +8
        vsrc += 128;
    };

    bf16x8 qaA0 = *reinterpret_cast<const bf16x8*>(qp + (size_t)(qbase + l15) * HD + quad * 8);
    bf16x8 qaA1 = *reinterpret_cast<const bf16x8*>(qp + (size_t)(qbase + l15) * HD + 32 + quad * 8);
    bf16x8 qaB0 = *reinterpret_cast<const bf16x8*>(qp + (size_t)(qbase + 16 + l15) * HD + quad * 8);
    bf16x8 qaB1 = *reinterpret_cast<const bf16x8*>(qp + (size_t)(qbase + 16 + l15) * HD + 32 + quad * 8);

    f32x4 OA[4], OB[4];
    #pragma unroll
    for (int i = 0; i < 4; ++i) { OA[i] = (f32x4){0.f, 0.f, 0.f, 0.f}; OB[i] = (f32x4){0.f, 0.f, 0.f, 0.f}; }
    float liA = 0.f, liB = 0.f;

    int sx = l15 & 7;

    auto compute = [&](const unsigned char* kb, const unsigned char* vbb) {
        f32x4 sA0[2], sA1[2], sB0[2], sB1[2];
        // --- QK burst: both chunks, 16 independent MFMAs ---
        #pragma unroll
        for (int s = 0; s < 2; ++s) {
            int r0 = (s * 32 + l15) * 128;
            bf16x8 k00 = *reinterpret_cast<const bf16x8*>(kb + r0 + ((quad ^ sx) * 16));
            bf16x8 k01 = *reinterpret_cast<const bf16x8*>(kb + r0 + (((quad + 4) ^ sx) * 16));
            bf16x8 k10 = *reinterpret_cast<const bf16x8*>(kb + r0 + 2048 + ((quad ^ sx) * 16));
            bf16x8 k11 = *reinterpret_cast<const bf16x8*>(kb + r0 + 2048 + (((quad + 4) ^ sx) * 16));
            sA0[s] = (f32x4){0.f,0.f,0.f,0.f};  sA1[s] = (f32x4){0.f,0.f,0.f,0.f};
            sB0[s] = (f32x4){0.f,0.f,0.f,0.f};  sB1[s] = (f32x4){0.f,0.f,0.f,0.f};
            sA0[s] = MFMA16(k00, qaA0, sA0[s]);  sA0[s] = MFMA16(k01, qaA1, sA0[s]);
            sA1[s] = MFMA16(k10, qaA0, sA1[s]);  sA1[s] = MFMA16(k11, qaA1, sA1[s]);
            sB0[s] = MFMA16(k00, qaB0, sB0[s]);  sB0[s] = MFMA16(k01, qaB1, sB0[s]);
            sB1[s] = MFMA16(k10, qaB0, sB1[s]);  sB1[s] = MFMA16(k11, qaB1, sB1[s]);
        }
        // --- exp / pack / PV per chunk ---
        #pragma unroll
        for (int s = 0; s < 2; ++s) {
            f32x4 pA0, pA1, pB0, pB1;
            #pragma unroll
            for (int r = 0; r < 4; ++r) {
                pA0[r] = EXP2F(sA0[s][r]);  pA1[r] = EXP2F(sA1[s][r]);
                pB0[r] = EXP2F(sB0[s][r]);  pB1[r] = EXP2F(sB1[s][r]);
            }
            liA += (pA0[0] + pA0[1] + pA0[2] + pA0[3]) + (pA1[0] + pA1[1] + pA1[2] + pA1[3]);
            liB += (pB0[0] + pB0[1] + pB0[2] + pB0[3]) + (pB1[0] + pB1[1] + pB1[2] + pB1[3]);

            short4v fA0 = pk4(pA0), fA1 = pk4(pA1), fB0 = pk4(pB0), fB1 = pk4(pB1);

            #pragma unroll
            for (int dc = 0; dc < 4; ++dc) {
                int c0 = ((s * 4 + (quad >> 1)) ^ sx) * 16 + (quad & 1) * 8;
                int c1 = ((s * 4 + 2 + (quad >> 1)) ^ sx) * 16 + (quad & 1) * 8;
                const unsigned char* vrow = vbb + (dc * 16 + l15) * 128;
                short4v v0 = *reinterpret_cast<const short4v*>(vrow + c0);
                short4v v1 = *reinterpret_cast<const short4v*>(vrow + c1);
                OA[dc] = MFMAPV(fA0, v0, OA[dc]);
                OA[dc] = MFMAPV(fA1, v1, OA[dc]);
                OB[dc] = MFMAPV(fB0, v0, OB[dc]);
                OB[dc] = MFMAPV(fB1, v1, OB[dc]);
            }
        }
    };

    stage(0);
    __syncthreads();

    for (int p = 0; p < 16; ++p) {
        stage(1);
        compute(kbuf[0], vbuf[0]);
        __syncthreads();
        if (p < 15) stage(0);
        compute(kbuf[1], vbuf[1]);
        __syncthreads();
    }

    liA += __shfl_xor(liA, 16);  liA += __shfl_xor(liA, 32);
    liB += __shfl_xor(liB, 16);  liB += __shfl_xor(liB, 32);

    unsigned short* op = split ? op1 : op0;
    int b = bh >> 2, h = bh & 3;
    #pragma unroll
    for (int dc = 0; dc < 4; ++dc) {
        #pragma unroll
        for (int r = 0; r < 4; ++r) {
            int qA = qbase + quad * 4 + r;
            op[((size_t)(b * NN) + qA) * CC + h * HD + dc * 16 + l15]      = f2bf(OA[dc][r]);
            op[((size_t)(b * NN) + qA + 16) * CC + h * HD + dc * 16 + l15] = f2bf(OB[dc][r]);
        }
    }
    float* lp = lip + (size_t)split * (16 * NN) + (size_t)bh * NN + qbase;
    if (quad == 0)      lp[l15]      = liA;
    else if (quad == 1) lp[16 + l15] = liB;
}

// ---------------- kernel 5: combine k-split partials -> normalized ao (in place in op0) ----------------
__global__ void __launch_bounds__(256)
k_comb(unsigned short* ao, const unsigned short* __restrict__ p1, const float* __restrict__ lip) {
    int g = blockIdx.x * 256 + threadIdx.x;   // 524288 threads, 8 bf16 each
    int d8 = g & 7;
    int h  = (g >> 3) & 3;
    int n  = (g >> 5) & 4095;
    int b  = g >> 17;
    int bh = b * 4 + h;
    float li0 = lip[(size_t)bh * NN + n];
    float li1 = lip[(size_t)16 * NN + (size_t)bh * NN + n];
    float inv = 1.0f / (li0 + li1);
    size_t idx = ((size_t)(b * NN) + n) * CC + h * HD + d8 * 8;
    uint4 u0 = *reinterpret_cast<const uint4*>(ao + idx);
    uint4 u1 = *reinterpret_cast<const uint4*>(p1 + idx);
    const unsigned short* a0 = reinterpret_cast<const unsigned short*>(&u0);
    const unsigned short* a1 = reinterpret_cast<const unsigned short*>(&u1);
    alignas(16) unsigned short o8[8];
    #pragma unroll
    for (int i = 0; i < 8; ++i) {
        float f0 = __uint_as_float((unsigned)a0[i] << 16);
        float f1 = __uint_as_float((unsigned)a1[i] << 16);
        o8[i] = f2bf((f0 + f1) * inv);
    }
    *reinterpret_cast<uint4*>(ao + idx) = *reinterpret_cast<const uint4*>(o8);
}

// ---------------- kernel 6: proj GEMM 64x64 tile + bias + residual (fp32 out) ----------------
__global__ void __launch_bounds__(256)
k_proj(const unsigned short* __restrict__ ao, const unsigned short* __restrict__ wp,
       const float* __restrict__ pb, const float* __restrict__ x,
       float* __restrict__ out) {
    int bx = blockIdx.x, by = blockIdx.y;
    int t = threadIdx.x, wave = t >> 6, lane = t & 63;
    int l15 = lane & 15, quad = lane >> 4;
    int wm = wave >> 1, wn = wave & 1;

    __shared__ alignas(16) unsigned char At[2][4096];   // [64 rows][32 c]
    __shared__ alignas(16) unsigned char Bt[2][4096];   // [64 rows][32 c]

    const char* Ag = (const char*)wp + (size_t)by * 32768;
    const char* Bg = (const char*)ao + (size_t)bx * 32768;
    int row0 = t >> 2, slot = t & 3;
    size_t a0 = (size_t)row0 * 512 + slot * 16;
    unsigned int dst0 = wave * 1024;

    auto stage = [&](int buf, int kk) {
        size_t ko = (size_t)kk * 64;
        async_ld16(At[buf] + dst0, Ag + a0 + ko);
        async_ld16(Bt[buf] + dst0, Bg + a0 + ko);
    };

    f32x4 acc[2][2];
    #pragma unroll
    for (int i = 0; i < 2; ++i)
        #pragma unroll
        for (int j = 0; j < 2; ++j) acc[i][j] = (f32x4){0.f, 0.f, 0.f, 0.f};

    stage(0, 0);
    __syncthreads();

    for (int kk = 0; kk < 8; ++kk) {
        int cur = kk & 1;
        if (kk < 7) stage(cur ^ 1, kk + 1);
        bf16x8 af[2], bf[2];
        #pragma unroll
        for (int f = 0; f < 2; ++f) {
            af[f] = *reinterpret_cast<const bf16x8*>(At[cur] + (wm * 32 + f * 16 + l15) * 64 + quad * 16);
            bf[f] = *reinterpret_cast<const bf16x8*>(Bt[cur] + (wn * 32 + f * 16 + l15) * 64 + quad * 16);
        }
        #pragma unroll
        for (int fm = 0; fm < 2; ++fm)
            #pragma unroll
            for (int fn = 0; fn < 2; ++fn)
                acc[fm][fn] = MFMA16(af[fm], bf[fn], acc[fm][fn]);
        __syncthreads();
    }

    int nn0 = bx * 64;
    int b = nn0 >> 12, nbase = nn0 & 4095;
    #pragma unroll
    for (int fm = 0; fm < 2; ++fm) {
        int o = by * 64 + wm * 32 + fm * 16 + quad * 4;
        float bias[4];
        #pragma unroll
        for (int r = 0; r < 4; ++r) bias[r] = pb[o + r];
        #pragma unroll
        for (int fn = 0; fn < 2; ++fn) {
            int n = nbase + wn * 32 + fn * 16 + l15;
            #pragma unroll
            for (int r = 0; r < 4; ++r) {
                size_t idx = ((size_t)(b * CC + o + r)) * NN + n;
                out[idx] = acc[fm][fn][r] + bias[r] + x[idx];
            }
        }
    }
}

extern "C" void kernel_launch(void* const* d_in, const int* in_sizes, int n_in,
                              void* d_out, int out_size, void* d_ws, size_t ws_size,
                              hipStream_t stream) {
    const float* x     = (const float*)d_in[0];
    const float* gw    = (const float*)d_in[1];
    const float* gb    = (const float*)d_in[2];
    const float* qkvw  = (const float*)d_in[3];
    const float* qkvb  = (const float*)d_in[4];
    const float* projw = (const float*)d_in[5];
    const float* projb = (const float*)d_in[6];
    float* out = (float*)d_out;

    char* w = (char*)d_ws;
    size_t off = 0;
    unsigned short* ht = (unsigned short*)(w + off); off += (size_t)BB * NN * CC * 2;       // 8 MB (reused as split-1 partial)
    unsigned short* qt = (unsigned short*)(w + off); off += (size_t)BB * NH * NN * HD * 2;  // 8 MB
    unsigned short* kt = (unsigned short*)(w + off); off += (size_t)BB * NH * NN * HD * 2;  // 8 MB
    unsigned short* vt = (unsigned short*)(w + off); off += (size_t)BB * NH * HD * NN * 2;  // 8 MB
    unsigned short* ao = (unsigned short*)(w + off); off += (size_t)BB * NN * CC * 2;       // 8 MB (split-0 partial, then final)
    unsigned short* wqb = (unsigned short*)(w + off); off += (size_t)3 * CC * CC * 2;       // 384 KB
    unsigned short* wpb = (unsigned short*)(w + off); off += (size_t)CC * CC * 2;           // 128 KB
    float* stats = (float*)(w + off); off += BB * NG * 2 * sizeof(float);
    float* lip   = (float*)(w + off); off += (size_t)2 * 16 * NN * sizeof(float);           // 512 KB

    hipMemsetAsync(stats, 0, BB * NG * 2 * sizeof(float), stream);
    k_prep<<<1024, 256, 0, stream>>>(x, stats, qkvw, projw, wqb, wpb);
    k_gnapply<<<dim3(NN / 64, CC / 32, BB), 256, 0, stream>>>(x, gw, gb, stats, ht);
    k_qkv<<<dim3(BB * NN / 128, 6), 256, 0, stream>>>(ht, wqb, qkvb, qt, kt, vt);
    k_attn<<<dim3(NN / 128, BB * NH, 2), 256, 0, stream>>>(qt, kt, vt, ao, ht, lip);
    k_comb<<<2048, 256, 0, stream>>>(ao, ht, lip);
    k_proj<<<dim3(BB * NN / 64, CC / 64), 256, 0, stream>>>(ao, wpb, projb, x, out);
}

// Round 12
// 191.728 us; speedup vs baseline: 1.1192x; 1.1192x over previous
//
#include <hip/hip_runtime.h>
#include <hip/hip_bf16.h>

// Problem constants (B=4, C=256, H=W=64, groups=8, heads=4)
#define BB   4
#define CC   256
#define NN   4096      // H*W
#define NH   4
#define HD   64
#define NG   8
#define GSZ  32        // channels per group
#define EPSV 1e-5f
#define SCALE_L2E 0.18033688f   // 64^-0.5 * log2(e), folded into q so softmax uses raw exp2

typedef __bf16 bf16x8 __attribute__((ext_vector_type(8)));
typedef float  f32x4  __attribute__((ext_vector_type(4)));

#define MFMA16(a, b, c)  __builtin_amdgcn_mfma_f32_16x16x32_bf16((a), (b), (c), 0, 0, 0)

#if __has_builtin(__builtin_amdgcn_exp2f)
#define EXP2F __builtin_amdgcn_exp2f
#else
#define EXP2F exp2f
#endif

__device__ inline unsigned short f2bf(float f) {
    unsigned int u = __float_as_uint(f);
    u += 0x7fffu + ((u >> 16) & 1u);   // RNE
    return (unsigned short)(u >> 16);
}

// pack 8 fp32 -> 8 bf16 (truncate: uniform relative bias cancels in O/li) for PV A-operand
__device__ __forceinline__ bf16x8 pk8(const f32x4& p0, const f32x4& p1) {
    alignas(16) unsigned int u[4];
    u[0] = __builtin_amdgcn_perm(__float_as_uint(p0[1]), __float_as_uint(p0[0]), 0x07060302u);
    u[1] = __builtin_amdgcn_perm(__float_as_uint(p0[3]), __float_as_uint(p0[2]), 0x07060302u);
    u[2] = __builtin_amdgcn_perm(__float_as_uint(p1[1]), __float_as_uint(p1[0]), 0x07060302u);
    u[3] = __builtin_amdgcn_perm(__float_as_uint(p1[3]), __float_as_uint(p1[2]), 0x07060302u);
    return *reinterpret_cast<bf16x8*>(u);
}

// async global->LDS, 16B per lane; LDS dest is wave-uniform base + lane*16
__device__ __forceinline__ void async_ld16(void* lds, const void* g) {
    __builtin_amdgcn_global_load_lds(
        (const __attribute__((address_space(1))) unsigned int*)g,
        (__attribute__((address_space(3))) unsigned int*)lds, 16, 0, 0);
}

// ---------------- kernel 1: gn stats (blocks 0..255) + weight cvt (blocks 256..1023) ----------------
__global__ void k_prep(const float* __restrict__ x, float* __restrict__ stats,
                       const float* __restrict__ wq, const float* __restrict__ wp,
                       unsigned short* __restrict__ oq, unsigned short* __restrict__ op) {
    int blk = blockIdx.x;
    int t = threadIdx.x;
    if (blk >= 256) {   // weight conversion
        int i = (blk - 256) * 256 + t;
        if (i < 3 * CC * CC) oq[i] = f2bf(wq[i]);
        if (i < CC * CC)     op[i] = f2bf(wp[i]);
        return;
    }
    int b = blk >> 6, g = (blk >> 3) & 7, s = blk & 7;
    const float* p = x + ((size_t)(b * CC + g * GSZ)) * NN + s * 16384;
    float s0 = 0.f, s1 = 0.f;
    #pragma unroll
    for (int i = 0; i < 64; ++i) { float v = p[i * 256 + t]; s0 += v; s1 += v * v; }
    #pragma unroll
    for (int m = 1; m <= 32; m <<= 1) { s0 += __shfl_xor(s0, m); s1 += __shfl_xor(s1, m); }
    __shared__ float ls[8];
    int w = t >> 6;
    if ((t & 63) == 0) { ls[w * 2] = s0; ls[w * 2 + 1] = s1; }
    __syncthreads();
    if (t == 0) {
        float a0 = ls[0] + ls[2] + ls[4] + ls[6];
        float a1 = ls[1] + ls[3] + ls[5] + ls[7];
        atomicAdd(&stats[(b * NG + g) * 2 + 0], a0);
        atomicAdd(&stats[(b * NG + g) * 2 + 1], a1);
    }
}

// ------- kernel 2: groupnorm apply + transpose -> ht[b][n][c] (bf16) -------
__global__ void k_gnapply(const float* __restrict__ x, const float* __restrict__ gw,
                          const float* __restrict__ gb, const float* __restrict__ stats,
                          unsigned short* __restrict__ ht) {
    int b = blockIdx.z, ct = blockIdx.y, nt = blockIdx.x;
    int c0 = ct * 32, n0 = nt * 64;
    int t = threadIdx.x;
    __shared__ float tile[32][65];
    const float* xp = x + ((size_t)(b * CC + c0)) * NN + n0;
    int cl = t >> 6, nl = t & 63;
    #pragma unroll
    for (int p = 0; p < 8; ++p)
        tile[p * 4 + cl][nl] = xp[(size_t)(p * 4 + cl) * NN + nl];
    float sum = stats[(b * NG + ct) * 2 + 0];
    float ssq = stats[(b * NG + ct) * 2 + 1];
    float mean = sum * (1.0f / 131072.0f);
    float var  = ssq * (1.0f / 131072.0f) - mean * mean;
    float inv  = rsqrtf(var + EPSV);
    __syncthreads();
    int nw = t >> 2, ci = (t & 3) * 8;
    alignas(16) unsigned short o8[8];
    #pragma unroll
    for (int j = 0; j < 8; ++j) {
        int c = c0 + ci + j;
        float v = (tile[ci + j][nw] - mean) * inv * gw[c] + gb[c];
        o8[j] = f2bf(v);
    }
    *reinterpret_cast<uint4*>(ht + ((size_t)(b * NN + n0 + nw)) * CC + c0 + ci) =
        *reinterpret_cast<const uint4*>(o8);
}

// ---------------- kernel 3: QKV GEMM, 128x128 tile, double-buffered LDS ----------------
// V written with keys permuted within each 32-group (slot = ((c&15)>>2)*8 + (c&3) + ((c>>4)<<2))
// so the attention PV can use full-rate 16x16x32 MFMA with P fed directly as the A operand.
__global__ void __launch_bounds__(256)
k_qkv(const unsigned short* __restrict__ ht, const unsigned short* __restrict__ wq,
      const float* __restrict__ qb,
      unsigned short* __restrict__ qt, unsigned short* __restrict__ kt,
      unsigned short* __restrict__ vt) {
    int bx = blockIdx.x, by = blockIdx.y;
    int t = threadIdx.x, wave = t >> 6, lane = t & 63;
    int l15 = lane & 15, quad = lane >> 4;
    int wm = wave >> 1, wn = wave & 1;

    __shared__ alignas(16) unsigned char At[2][8192];   // [128 rows][32 c] bf16, 64B rows
    __shared__ alignas(16) unsigned char Bt[2][8192];

    const char* Ag = (const char*)wq + (size_t)by * 65536;
    const char* Bg = (const char*)ht + (size_t)bx * 65536;
    int row0 = t >> 2, slot = t & 3;                    // chunk t
    size_t a0 = (size_t)row0 * 512 + slot * 16;
    size_t a1 = a0 + 64 * 512;                          // chunk t+256
    unsigned int dst0 = wave * 1024;                    // lane*16 added by HW

    auto stage = [&](int buf, int kk) {
        size_t ko = (size_t)kk * 64;
        async_ld16(At[buf] + dst0,        Ag + a0 + ko);
        async_ld16(At[buf] + 4096 + dst0, Ag + a1 + ko);
        async_ld16(Bt[buf] + dst0,        Bg + a0 + ko);
        async_ld16(Bt[buf] + 4096 + dst0, Bg + a1 + ko);
    };

    f32x4 acc[4][4];
    #pragma unroll
    for (int i = 0; i < 4; ++i)
        #pragma unroll
        for (int j = 0; j < 4; ++j) acc[i][j] = (f32x4){0.f, 0.f, 0.f, 0.f};

    stage(0, 0);
    __syncthreads();

    for (int kk = 0; kk < 8; ++kk) {
        int cur = kk & 1;
        if (kk < 7) stage(cur ^ 1, kk + 1);
        bf16x8 af[4], bf[4];
        #pragma unroll
        for (int f = 0; f < 4; ++f) {
            af[f] = *reinterpret_cast<const bf16x8*>(At[cur] + (wm * 64 + f * 16 + l15) * 64 + quad * 16);
            bf[f] = *reinterpret_cast<const bf16x8*>(Bt[cur] + (wn * 64 + f * 16 + l15) * 64 + quad * 16);
        }
        #pragma unroll
        for (int fm = 0; fm < 4; ++fm)
            #pragma unroll
            for (int fn = 0; fn < 4; ++fn)
                acc[fm][fn] = MFMA16(af[fm], bf[fn], acc[fm][fn]);
        __syncthreads();
    }

    int s = by >> 1;
    int nn0 = bx * 128;
    int b = nn0 >> 12, nbase = nn0 & 4095;
    #pragma unroll
    for (int fm = 0; fm < 4; ++fm) {
        int o = by * 128 + wm * 64 + fm * 16 + quad * 4;
        int h = (o >> 6) & 3, d0 = o & 63;
        float bias[4];
        #pragma unroll
        for (int r = 0; r < 4; ++r) bias[r] = qb[o + r];
        #pragma unroll
        for (int fn = 0; fn < 4; ++fn) {
            int n = nbase + wn * 64 + fn * 16 + l15;
            if (s == 0) {
                alignas(8) unsigned short o4[4];
                #pragma unroll
                for (int r = 0; r < 4; ++r) o4[r] = f2bf((acc[fm][fn][r] + bias[r]) * SCALE_L2E);
                *reinterpret_cast<uint2*>(qt + (((size_t)(b * NH + h) * NN) + n) * HD + d0) =
                    *reinterpret_cast<const uint2*>(o4);
            } else if (s == 1) {
                alignas(8) unsigned short o4[4];
                #pragma unroll
                for (int r = 0; r < 4; ++r) o4[r] = f2bf(acc[fm][fn][r] + bias[r]);
                *reinterpret_cast<uint2*>(kt + (((size_t)(b * NH + h) * NN) + n) * HD + d0) =
                    *reinterpret_cast<const uint2*>(o4);
            } else {
                // permuted key slot within each 32-group (see k_attn PV)
                int cl = n & 31;
                int pn = (n & ~31) | (((cl & 12) << 1) | ((cl >> 4) << 2) | (cl & 3));
                #pragma unroll
                for (int r = 0; r < 4; ++r)
                    vt[((size_t)(b * NH + h) * HD + d0 + r) * NN + pn] = f2bf(acc[fm][fn][r] + bias[r]);
            }
        }
    }
}

// ---------------- kernel 4: flash attention, k-split 2, full-rate PV (16x16x32) ----------------
// grid (32 q-tiles of 128, B*NH, 2 key-splits); block 256 = 4 waves; wave owns 32 queries.
// S^T C-layout (q=l15, key=quad*4+r) packs directly into the 16x16x32 A-operand
// (k=quad*8+j) because V's key axis is pre-permuted to slot order by k_qkv:
// slots quad*8..+3 = keys 4q..4q+3 (s0 regs), slots quad*8+4..+7 = keys 16+4q..+3 (s1 regs).
// PV per 32-key chunk: 8 full-rate MFMAs (was 16 half-rate 16x16x16).
__global__ void __launch_bounds__(256, 4)
k_attn(const unsigned short* __restrict__ qt, const unsigned short* __restrict__ kt,
       const unsigned short* __restrict__ vt,
       unsigned short* __restrict__ op0, unsigned short* __restrict__ op1,
       float* __restrict__ lip) {
    int bh = blockIdx.y;
    int split = blockIdx.z;
    int t = threadIdx.x, wave = t >> 6, lane = t & 63;
    int l15 = lane & 15, quad = lane >> 4;
    int qbase = blockIdx.x * 128 + wave * 32;
    int kbase = split * 2048;
    const unsigned short* qp = qt + (size_t)bh * NN * HD;
    const unsigned short* kp = kt + (size_t)bh * NN * HD;
    const unsigned short* vp = vt + (size_t)bh * HD * NN;

    __shared__ alignas(16) unsigned char kbuf[2][8192];   // [64 keys][128 B]
    __shared__ alignas(16) unsigned char vbuf[2][8192];   // [64 d][128 B] (keys slot-permuted)

    int lr8 = lane >> 3, lc8 = lane & 7;
    int swz = lc8 ^ lr8;
    const char* ksrc = (const char*)kp + (size_t)(kbase + wave * 16 + lr8) * 128 + swz * 16;
    const char* vsrc = (const char*)vp + (size_t)(wave * 16 + lr8) * 8192 + (size_t)kbase * 2 + swz * 16;
    unsigned int dstw = wave * 2048;                // + lane*16 by HW

    auto stage = [&](int buf) {                     // stages next 64-key tile, advances
        async_ld16(kbuf[buf] + dstw,        ksrc);
        async_ld16(kbuf[buf] + dstw + 1024, ksrc + 1024);       // K rows +8
        ksrc += 8192;
        async_ld16(vbuf[buf] + dstw,        vsrc);
        async_ld16(vbuf[buf] + dstw + 1024, vsrc + 8 * 8192);   // d-rows +8
        vsrc += 128;
    };

    bf16x8 qaA0 = *reinterpret_cast<const bf16x8*>(qp + (size_t)(qbase + l15) * HD + quad * 8);
    bf16x8 qaA1 = *reinterpret_cast<const bf16x8*>(qp + (size_t)(qbase + l15) * HD + 32 + quad * 8);
    bf16x8 qaB0 = *reinterpret_cast<const bf16x8*>(qp + (size_t)(qbase + 16 + l15) * HD + quad * 8);
    bf16x8 qaB1 = *reinterpret_cast<const bf16x8*>(qp + (size_t)(qbase + 16 + l15) * HD + 32 + quad * 8);

    f32x4 OA[4], OB[4];
    #pragma unroll
    for (int i = 0; i < 4; ++i) { OA[i] = (f32x4){0.f, 0.f, 0.f, 0.f}; OB[i] = (f32x4){0.f, 0.f, 0.f, 0.f}; }
    float liA = 0.f, liB = 0.f;

    int sx = l15 & 7;

    auto compute = [&](const unsigned char* kb, const unsigned char* vbb) {
        f32x4 sA0[2], sA1[2], sB0[2], sB1[2];
        // --- QK burst: both chunks, 16 independent MFMAs ---
        #pragma unroll
        for (int s = 0; s < 2; ++s) {
            int r0 = (s * 32 + l15) * 128;
            bf16x8 k00 = *reinterpret_cast<const bf16x8*>(kb + r0 + ((quad ^ sx) * 16));
            bf16x8 k01 = *reinterpret_cast<const bf16x8*>(kb + r0 + (((quad + 4) ^ sx) * 16));
            bf16x8 k10 = *reinterpret_cast<const bf16x8*>(kb + r0 + 2048 + ((quad ^ sx) * 16));
            bf16x8 k11 = *reinterpret_cast<const bf16x8*>(kb + r0 + 2048 + (((quad + 4) ^ sx) * 16));
            sA0[s] = (f32x4){0.f,0.f,0.f,0.f};  sA1[s] = (f32x4){0.f,0.f,0.f,0.f};
            sB0[s] = (f32x4){0.f,0.f,0.f,0.f};  sB1[s] = (f32x4){0.f,0.f,0.f,0.f};
            sA0[s] = MFMA16(k00, qaA0, sA0[s]);  sA0[s] = MFMA16(k01, qaA1, sA0[s]);
            sA1[s] = MFMA16(k10, qaA0, sA1[s]);  sA1[s] = MFMA16(k11, qaA1, sA1[s]);
            sB0[s] = MFMA16(k00, qaB0, sB0[s]);  sB0[s] = MFMA16(k01, qaB1, sB0[s]);
            sB1[s] = MFMA16(k10, qaB0, sB1[s]);  sB1[s] = MFMA16(k11, qaB1, sB1[s]);
        }
        // --- exp / pack / PV per chunk ---
        #pragma unroll
        for (int s = 0; s < 2; ++s) {
            f32x4 pA0, pA1, pB0, pB1;
            #pragma unroll
            for (int r = 0; r < 4; ++r) {
                pA0[r] = EXP2F(sA0[s][r]);  pA1[r] = EXP2F(sA1[s][r]);
                pB0[r] = EXP2F(sB0[s][r]);  pB1[r] = EXP2F(sB1[s][r]);
            }
            liA += (pA0[0] + pA0[1] + pA0[2] + pA0[3]) + (pA1[0] + pA1[1] + pA1[2] + pA1[3]);
            liB += (pB0[0] + pB0[1] + pB0[2] + pB0[3]) + (pB1[0] + pB1[1] + pB1[2] + pB1[3]);

            bf16x8 fA = pk8(pA0, pA1);   // A-frag: slots quad*8..+7 of this chunk
            bf16x8 fB = pk8(pB0, pB1);

            #pragma unroll
            for (int dc = 0; dc < 4; ++dc) {
                const unsigned char* vrow = vbb + (dc * 16 + l15) * 128;
                bf16x8 vv = *reinterpret_cast<const bf16x8*>(vrow + (((s * 4 + quad) ^ sx) * 16));
                OA[dc] = MFMA16(fA, vv, OA[dc]);   // D: row=q=quad*4+r, col=d=l15
                OB[dc] = MFMA16(fB, vv, OB[dc]);
            }
        }
    };

    stage(0);
    __syncthreads();

    for (int p = 0; p < 16; ++p) {
        stage(1);
        compute(kbuf[0], vbuf[0]);
        __syncthreads();
        if (p < 15) stage(0);
        compute(kbuf[1], vbuf[1]);
        __syncthreads();
    }

    liA += __shfl_xor(liA, 16);  liA += __shfl_xor(liA, 32);
    liB += __shfl_xor(liB, 16);  liB += __shfl_xor(liB, 32);

    unsigned short* op = split ? op1 : op0;
    int b = bh >> 2, h = bh & 3;
    #pragma unroll
    for (int dc = 0; dc < 4; ++dc) {
        #pragma unroll
        for (int r = 0; r < 4; ++r) {
            int qA = qbase + quad * 4 + r;
            op[((size_t)(b * NN) + qA) * CC + h * HD + dc * 16 + l15]      = f2bf(OA[dc][r]);
            op[((size_t)(b * NN) + qA + 16) * CC + h * HD + dc * 16 + l15] = f2bf(OB[dc][r]);
        }
    }
    float* lp = lip + (size_t)split * (16 * NN) + (size_t)bh * NN + qbase;
    if (quad == 0)      lp[l15]      = liA;
    else if (quad == 1) lp[16 + l15] = liB;
}

// ---------------- kernel 5: combine k-split partials -> normalized ao (in place in op0) ----------------
__global__ void __launch_bounds__(256)
k_comb(unsigned short* ao, const unsigned short* __restrict__ p1, const float* __restrict__ lip) {
    int g = blockIdx.x * 256 + threadIdx.x;   // 524288 threads, 8 bf16 each
    int d8 = g & 7;
    int h  = (g >> 3) & 3;
    int n  = (g >> 5) & 4095;
    int b  = g >> 17;
    int bh = b * 4 + h;
    float li0 = lip[(size_t)bh * NN + n];
    float li1 = lip[(size_t)16 * NN + (size_t)bh * NN + n];
    float inv = 1.0f / (li0 + li1);
    size_t idx = ((size_t)(b * NN) + n) * CC + h * HD + d8 * 8;
    uint4 u0 = *reinterpret_cast<const uint4*>(ao + idx);
    uint4 u1 = *reinterpret_cast<const uint4*>(p1 + idx);
    const unsigned short* a0 = reinterpret_cast<const unsigned short*>(&u0);
    const unsigned short* a1 = reinterpret_cast<const unsigned short*>(&u1);
    alignas(16) unsigned short o8[8];
    #pragma unroll
    for (int i = 0; i < 8; ++i) {
        float f0 = __uint_as_float((unsigned)a0[i] << 16);
        float f1 = __uint_as_float((unsigned)a1[i] << 16);
        o8[i] = f2bf((f0 + f1) * inv);
    }
    *reinterpret_cast<uint4*>(ao + idx) = *reinterpret_cast<const uint4*>(o8);
}

// ---------------- kernel 6: proj GEMM 64x64 tile + bias + residual (fp32 out) ----------------
__global__ void __launch_bounds__(256)
k_proj(const unsigned short* __restrict__ ao, const unsigned short* __restrict__ wp,
       const float* __restrict__ pb, const float* __restrict__ x,
       float* __restrict__ out) {
    int bx = blockIdx.x, by = blockIdx.y;
    int t = threadIdx.x, wave = t >> 6, lane = t & 63;
    int l15 = lane & 15, quad = lane >> 4;
    int wm = wave >> 1, wn = wave & 1;

    __shared__ alignas(16) unsigned char At[2][4096];   // [64 rows][32 c]
    __shared__ alignas(16) unsigned char Bt[2][4096];   // [64 rows][32 c]

    const char* Ag = (const char*)wp + (size_t)by * 32768;
    const char* Bg = (const char*)ao + (size_t)bx * 32768;
    int row0 = t >> 2, slot = t & 3;
    size_t a0 = (size_t)row0 * 512 + slot * 16;
    unsigned int dst0 = wave * 1024;

    auto stage = [&](int buf, int kk) {
        size_t ko = (size_t)kk * 64;
        async_ld16(At[buf] + dst0, Ag + a0 + ko);
        async_ld16(Bt[buf] + dst0, Bg + a0 + ko);
    };

    f32x4 acc[2][2];
    #pragma unroll
    for (int i = 0; i < 2; ++i)
        #pragma unroll
        for (int j = 0; j < 2; ++j) acc[i][j] = (f32x4){0.f, 0.f, 0.f, 0.f};

    stage(0, 0);
    __syncthreads();

    for (int kk = 0; kk < 8; ++kk) {
        int cur = kk & 1;
        if (kk < 7) stage(cur ^ 1, kk + 1);
        bf16x8 af[2], bf[2];
        #pragma unroll
        for (int f = 0; f < 2; ++f) {
            af[f] = *reinterpret_cast<const bf16x8*>(At[cur] + (wm * 32 + f * 16 + l15) * 64 + quad * 16);
            bf[f] = *reinterpret_cast<const bf16x8*>(Bt[cur] + (wn * 32 + f * 16 + l15) * 64 + quad * 16);
        }
        #pragma unroll
        for (int fm = 0; fm < 2; ++fm)
            #pragma unroll
            for (int fn = 0; fn < 2; ++fn)
                acc[fm][fn] = MFMA16(af[fm], bf[fn], acc[fm][fn]);
        __syncthreads();
    }

    int nn0 = bx * 64;
    int b = nn0 >> 12, nbase = nn0 & 4095;
    #pragma unroll
    for (int fm = 0; fm < 2; ++fm) {
        int o = by * 64 + wm * 32 + fm * 16 + quad * 4;
        float bias[4];
        #pragma unroll
        for (int r = 0; r < 4; ++r) bias[r] = pb[o + r];
        #pragma unroll
        for (int fn = 0; fn < 2; ++fn) {
            int n = nbase + wn * 32 + fn * 16 + l15;
            #pragma unroll
            for (int r = 0; r < 4; ++r) {
                size_t idx = ((size_t)(b * CC + o + r)) * NN + n;
                out[idx] = acc[fm][fn][r] + bias[r] + x[idx];
            }
        }
    }
}

extern "C" void kernel_launch(void* const* d_in, const int* in_sizes, int n_in,
                              void* d_out, int out_size, void* d_ws, size_t ws_size,
                              hipStream_t stream) {
    const float* x     = (const float*)d_in[0];
    const float* gw    = (const float*)d_in[1];
    const float* gb    = (const float*)d_in[2];
    const float* qkvw  = (const float*)d_in[3];
    const float* qkvb  = (const float*)d_in[4];
    const float* projw = (const float*)d_in[5];
    const float* projb = (const float*)d_in[6];
    float* out = (float*)d_out;

    char* w = (char*)d_ws;
    size_t off = 0;
    unsigned short* ht = (unsigned short*)(w + off); off += (size_t)BB * NN * CC * 2;       // 8 MB (reused as split-1 partial)
    unsigned short* qt = (unsigned short*)(w + off); off += (size_t)BB * NH * NN * HD * 2;  // 8 MB
    unsigned short* kt = (unsigned short*)(w + off); off += (size_t)BB * NH * NN * HD * 2;  // 8 MB
    unsigned short* vt = (unsigned short*)(w + off); off += (size_t)BB * NH * HD * NN * 2;  // 8 MB
    unsigned short* ao = (unsigned short*)(w + off); off += (size_t)BB * NN * CC * 2;       // 8 MB (split-0 partial, then final)
    unsigned short* wqb = (unsigned short*)(w + off); off += (size_t)3 * CC * CC * 2;       // 384 KB
    unsigned short* wpb = (unsigned short*)(w + off); off += (size_t)CC * CC * 2;           // 128 KB
    float* stats = (float*)(w + off); off += BB * NG * 2 * sizeof(float);
    float* lip   = (float*)(w + off); off += (size_t)2 * 16 * NN * sizeof(float);           // 512 KB

    hipMemsetAsync(stats, 0, BB * NG * 2 * sizeof(float), stream);
    k_prep<<<1024, 256, 0, stream>>>(x, stats, qkvw, projw, wqb, wpb);
    k_gnapply<<<dim3(NN / 64, CC / 32, BB), 256, 0, stream>>>(x, gw, gb, stats, ht);
    k_qkv<<<dim3(BB * NN / 128, 6), 256, 0, stream>>>(ht, wqb, qkvb, qt, kt, vt);
    k_attn<<<dim3(NN / 128, BB * NH, 2), 256, 0, stream>>>(qt, kt, vt, ao, ht, lip);
    k_comb<<<2048, 256, 0, stream>>>(ao, ht, lip);
    k_proj<<<dim3(BB * NN / 64, CC / 64), 256, 0, stream>>>(ao, wpb, projb, x, out);
}